// Round 1
// baseline (2315.528 us; speedup 1.0000x reference)
//
#include <hip/hip_runtime.h>

// Problem shape (fixed by reference setup_inputs): phi (B,2,H,W) f32 -> out (B,1,H,W) f32
constexpr int H = 2048;
constexpr int W = 2048;

__global__ __launch_bounds__(256)
void splat_kernel(const float* __restrict__ phi, float* __restrict__ out,
                  long long totalQuads) {
    long long tid = (long long)blockIdx.x * blockDim.x + threadIdx.x;
    if (tid >= totalQuads) return;

    const int quadsPerRow = W / 4;               // 512
    long long rowId = tid / quadsPerRow;         // b*H + i
    int q = (int)(tid - rowId * quadsPerRow);
    int b = (int)(rowId / H);
    int i = (int)(rowId - (long long)b * H);
    int j = q * 4;

    const float* phiB = phi + (long long)b * 2 * H * W;
    float4 p0 = *reinterpret_cast<const float4*>(phiB + (long long)i * W + j);
    float4 p1 = *reinterpret_cast<const float4*>(phiB + (long long)H * W + (long long)i * W + j);

    float* outb = out + (long long)b * H * W;

    const float pxs[4] = {p0.x, p0.y, p0.z, p0.w};
    const float pys[4] = {p1.x, p1.y, p1.z, p1.w};

    #pragma unroll
    for (int e = 0; e < 4; ++e) {
        float x = (float)i + pxs[e];
        float y = (float)(j + e) + pys[e];
        float x0f = floorf(x);
        float y0f = floorf(y);
        float wx1 = x - x0f, wy1 = y - y0f;
        float wx0 = 1.0f - wx1, wy0 = 1.0f - wy1;

        int ix0 = (int)x0f % H; if (ix0 < 0) ix0 += H;
        int iy0 = (int)y0f % W; if (iy0 < 0) iy0 += W;
        int ix1 = ix0 + 1; if (ix1 == H) ix1 = 0;
        int iy1 = iy0 + 1; if (iy1 == W) iy1 = 0;

        atomicAdd(outb + (long long)ix0 * W + iy0, wx0 * wy0);
        atomicAdd(outb + (long long)ix0 * W + iy1, wx0 * wy1);
        atomicAdd(outb + (long long)ix1 * W + iy0, wx1 * wy0);
        atomicAdd(outb + (long long)ix1 * W + iy1, wx1 * wy1);
    }
}

extern "C" void kernel_launch(void* const* d_in, const int* in_sizes, int n_in,
                              void* d_out, int out_size, void* d_ws, size_t ws_size,
                              hipStream_t stream) {
    const float* phi = (const float*)d_in[0];
    float* out = (float*)d_out;

    // out_size = B*H*W; zero it every call (harness poisons, never re-zeros).
    hipMemsetAsync(out, 0, (size_t)out_size * sizeof(float), stream);

    long long totalQuads = (long long)out_size / 4;   // 4 pixels per thread
    int block = 256;
    long long grid = (totalQuads + block - 1) / block;
    splat_kernel<<<(dim3)(unsigned)grid, block, 0, stream>>>(phi, out, totalQuads);
}

// Round 2
// 359.302 us; speedup vs baseline: 6.4445x; 6.4445x over previous
//
#include <hip/hip_runtime.h>

// Problem shape (fixed by reference setup_inputs): phi (B,2,H,W) f32 -> out (B,1,H,W) f32
constexpr int H = 2048;
constexpr int W = 2048;
constexpr int TH = 64;          // tile rows per block
constexpr int TW = 64;          // tile cols per block
constexpr int HALO = 8;         // |phi| ~ N(0,1); max|z| over 33M samples ~5.7 << 8
constexpr int LH = TH + 2 * HALO;   // 80
constexpr int LW = TW + 2 * HALO;   // 80

__global__ __launch_bounds__(256)
void splat_tile_kernel(const float* __restrict__ phi, float* __restrict__ out) {
    __shared__ float tile[LH * LW];   // 25.6 KB -> ~6 blocks/CU

    const int tilesPerRow = W / TW;                    // 32
    const int tilesPerImg = (H / TH) * tilesPerRow;    // 1024
    int id = blockIdx.x;
    int b  = id / tilesPerImg;
    int t  = id - b * tilesPerImg;
    int ti = t / tilesPerRow;
    int tj = t - ti * tilesPerRow;
    int i0 = ti * TH;
    int j0 = tj * TW;

    for (int k = threadIdx.x; k < LH * LW; k += 256) tile[k] = 0.0f;
    __syncthreads();

    const float* phiB = phi + (size_t)b * 2 * H * W;
    float* outb = out + (size_t)b * H * W;

    // 64 rows x 16 quads/row = 1024 float4-quads; 4 quads per thread, coalesced.
    #pragma unroll
    for (int qq = 0; qq < 4; ++qq) {
        int q  = threadIdx.x + qq * 256;
        int r  = q >> 4;              // row within tile
        int c4 = (q & 15) << 2;       // col within tile (quad start)
        int i  = i0 + r;
        int j  = j0 + c4;
        const float4 p0 = *reinterpret_cast<const float4*>(phiB + (size_t)i * W + j);
        const float4 p1 = *reinterpret_cast<const float4*>(phiB + (size_t)H * W + (size_t)i * W + j);
        const float pxs[4] = {p0.x, p0.y, p0.z, p0.w};
        const float pys[4] = {p1.x, p1.y, p1.z, p1.w};

        #pragma unroll
        for (int e = 0; e < 4; ++e) {
            float x = (float)i + pxs[e];
            float y = (float)(j + e) + pys[e];
            float x0f = floorf(x), y0f = floorf(y);
            float wx1 = x - x0f, wy1 = y - y0f;
            float wx0 = 1.0f - wx1, wy0 = 1.0f - wy1;
            int ix0 = (int)x0f;       // raw (can be <0 or >=H), near i
            int iy0 = (int)y0f;
            int lx = ix0 - (i0 - HALO);
            int ly = iy0 - (j0 - HALO);
            if ((unsigned)lx < (unsigned)(LH - 1) && (unsigned)ly < (unsigned)(LW - 1)) {
                // fast path: all four corners inside the LDS tile
                float* base = tile + lx * LW + ly;
                atomicAdd(base,          wx0 * wy0);
                atomicAdd(base + 1,      wx0 * wy1);
                atomicAdd(base + LW,     wx1 * wy0);
                atomicAdd(base + LW + 1, wx1 * wy1);
            } else {
                // fallback (statistically never for N(0,1); correctness for any input)
                int gx0 = ix0 % H; if (gx0 < 0) gx0 += H;
                int gy0 = iy0 % W; if (gy0 < 0) gy0 += W;
                int gx1 = gx0 + 1; if (gx1 == H) gx1 = 0;
                int gy1 = gy0 + 1; if (gy1 == W) gy1 = 0;
                atomicAdd(outb + (size_t)gx0 * W + gy0, wx0 * wy0);
                atomicAdd(outb + (size_t)gx0 * W + gy1, wx0 * wy1);
                atomicAdd(outb + (size_t)gx1 * W + gy0, wx1 * wy0);
                atomicAdd(outb + (size_t)gx1 * W + gy1, wx1 * wy1);
            }
        }
    }
    __syncthreads();

    // flush LDS tile -> global with wrap; coalesced along columns; skip zeros
    for (int k = threadIdx.x; k < LH * LW; k += 256) {
        float v = tile[k];
        if (v != 0.0f) {
            int r = k / LW;
            int c = k - r * LW;
            int gr = (i0 - HALO + r) & (H - 1);   // pow2 wrap (works for negatives)
            int gc = (j0 - HALO + c) & (W - 1);
            atomicAdd(outb + (size_t)gr * W + gc, v);
        }
    }
}

extern "C" void kernel_launch(void* const* d_in, const int* in_sizes, int n_in,
                              void* d_out, int out_size, void* d_ws, size_t ws_size,
                              hipStream_t stream) {
    const float* phi = (const float*)d_in[0];
    float* out = (float*)d_out;

    // out_size = B*H*W; zero each call (harness poisons and never re-zeros)
    hipMemsetAsync(out, 0, (size_t)out_size * sizeof(float), stream);

    int B = out_size / (H * W);
    int grid = B * (H / TH) * (W / TW);   // 4096 blocks
    splat_tile_kernel<<<grid, 256, 0, stream>>>(phi, out);
}